// Round 9
// baseline (67.119 us; speedup 1.0000x reference)
//
#include <hip/hip_runtime.h>

#define NB   16
#define NC   3
#define NH   512
#define NW   512
#define OUTH 506
#define OUTW 506
#define NCHK 21          // 19 chunks x 24 rows + 2 chunks x 25 rows = 506
#define NSLOT 10         // ring slots; 2-rows-ahead staging (see race analysis)
#define NBLK (NB * NC * NCHK)   // 1008 blocks

// -------- kernel 0: init workspace (runs every call; harness doesn't re-poison)
__global__ void ssim_init_ws(unsigned int* mn, unsigned int* mx, float* sum) {
    int i = threadIdx.x;
    if (i < NB) { mn[i] = 0x7f7fffffu; mx[i] = 0u; sum[i] = 0.0f; }
}

// -------- kernel 1: per-image min/max of pred (values >= 0 -> uint-bit order == float order)
__global__ __launch_bounds__(256) void ssim_minmax(const float* __restrict__ pred,
                                                   unsigned int* __restrict__ mn,
                                                   unsigned int* __restrict__ mx) {
    int b = blockIdx.y;
    const float4* p4 = (const float4*)(pred + (size_t)b * (NC * NH * NW));
    const int n4 = (NC * NH * NW) / 4;
    float lmin = 3.4e38f, lmax = -3.4e38f;
    for (int i = blockIdx.x * blockDim.x + threadIdx.x; i < n4; i += gridDim.x * blockDim.x) {
        float4 v = p4[i];
        lmin = fminf(lmin, fminf(fminf(v.x, v.y), fminf(v.z, v.w)));
        lmax = fmaxf(lmax, fmaxf(fmaxf(v.x, v.y), fmaxf(v.z, v.w)));
    }
    #pragma unroll
    for (int off = 32; off; off >>= 1) {
        lmin = fminf(lmin, __shfl_down(lmin, off, 64));
        lmax = fmaxf(lmax, __shfl_down(lmax, off, 64));
    }
    __shared__ float smin[4], smax[4];
    int wid = threadIdx.x >> 6, lane = threadIdx.x & 63;
    if (lane == 0) { smin[wid] = lmin; smax[wid] = lmax; }
    __syncthreads();
    if (threadIdx.x == 0) {
        float m = fminf(fminf(smin[0], smin[1]), fminf(smin[2], smin[3]));
        float M = fmaxf(fmaxf(smax[0], smax[1]), fmaxf(smax[2], smax[3]));
        atomicMin(&mn[b], __float_as_uint(m));
        atomicMax(&mx[b], __float_as_uint(M));
    }
}

// -------- kernel 2: LDS-ring SSIM, software-pipelined
// Ring race analysis (N=10, 2-ahead staging, 1 barrier/iter):
//   iter k: leave-reads slot (k+3)%10 (row k-7), enter-prefetch slot (k+1)%10
//           (row k+1, written at iter k-1, valid since barrier k-1),
//           writes slot (k+2)%10 (row k+2, loaded at iter k-1) -> disjoint.
//   slot (k+2)%10 last held row k-8, last read (leave) at iter k-1,
//   separated from the write by the end-of-iter-(k-1) barrier.
__global__ __launch_bounds__(256, 4) void ssim_main(const float* __restrict__ tin,
                                                    const float* __restrict__ pin,
                                                    const unsigned int* __restrict__ mn,
                                                    const unsigned int* __restrict__ mx,
                                                    float* __restrict__ sum) {
    __shared__ float ring[NSLOT][2][NW];   // 40,960 B exactly -> 4 blocks/CU

    const int li    = threadIdx.x;
    const int imgch = blockIdx.x / NCHK;
    const int chunk = blockIdx.x - imgch * NCHK;
    const int b     = imgch / NC;
    const int r0    = chunk * 24 + max(0, chunk - 19);  // chunks 19,20 have 25 rows
    const int rpc   = (chunk >= 19) ? 25 : 24;
    const int kend  = rpc + 6;
    const int lastr = rpc + 5;

    const float* tbase = tin + (size_t)imgch * (NH * NW) + (size_t)r0 * NW;
    const float* pbase = pin + (size_t)imgch * (NH * NW) + (size_t)r0 * NW;

    const float dr  = __uint_as_float(mx[b]) - __uint_as_float(mn[b]);
    const float c1  = (0.01f * dr) * (0.01f * dr);
    const float c2  = (0.03f * dr) * (0.03f * dr);
    const float C1s = 2401.0f * c1;   // 49^2 * c1
    const float C2s = 2352.0f * c2;   // 48*49 * c2

    // staging role: waves 0-1 stage t rows, waves 2-3 stage p rows (float4)
    const int  sarr = (li < 128) ? 0 : 1;
    const int  scol = (li & 127) * 4;
    const float* gsrc = ((sarr == 0) ? tbase : pbase) + scol;

    // read-column base; threads 253-255 clamp (outputs masked)
    const int rc = 2 * min(li, 252);
    const bool valid = (li < 253);

    float st[8], sp[8], stt[8], spp[8], stp[8];
    #pragma unroll
    for (int i = 0; i < 8; ++i) { st[i]=0.f; sp[i]=0.f; stt[i]=0.f; spp[i]=0.f; stp[i]=0.f; }

    float acc = 0.f;

    // prologue: stage rows 0,1 into slots 0,1; row 2 -> gO (as if loaded iter -1)
    {
        float4 r0v = *(const float4*)(gsrc);
        float4 r1v = *(const float4*)(gsrc + NW);
        *(float4*)&ring[0][sarr][scol] = r0v;
        *(float4*)&ring[1][sarr][scol] = r1v;
    }
    float4 gO = *(const float4*)(gsrc + 2 * NW);
    float4 gE;
    __syncthreads();

    // prefetched enter registers (row k at iter k), filled for row 0 now
    float2 ea0, ea1, ea2, ea3, ec0, ec1, ec2, ec3;
    ea0 = *(const float2*)&ring[0][0][rc + 0];
    ea1 = *(const float2*)&ring[0][0][rc + 2];
    ea2 = *(const float2*)&ring[0][0][rc + 4];
    ea3 = *(const float2*)&ring[0][0][rc + 6];
    ec0 = *(const float2*)&ring[0][1][rc + 0];
    ec1 = *(const float2*)&ring[0][1][rc + 2];
    ec2 = *(const float2*)&ring[0][1][rc + 4];
    ec3 = *(const float2*)&ring[0][1][rc + 6];

    int se = 0;   // k % NSLOT

#define APPLY2(I0, A_, C_, SGN) do {                                \
        st[I0]     += SGN A_.x;  sp[I0]     += SGN C_.x;            \
        stt[I0]     = fmaf(SGN A_.x, A_.x, stt[I0]);                \
        spp[I0]     = fmaf(SGN C_.x, C_.x, spp[I0]);                \
        stp[I0]     = fmaf(SGN A_.x, C_.x, stp[I0]);                \
        st[I0 + 1] += SGN A_.y;  sp[I0 + 1] += SGN C_.y;            \
        stt[I0 + 1] = fmaf(SGN A_.y, A_.y, stt[I0 + 1]);            \
        spp[I0 + 1] = fmaf(SGN C_.y, C_.y, spp[I0 + 1]);            \
        stp[I0 + 1] = fmaf(SGN A_.y, C_.y, stp[I0 + 1]);            \
    } while (0)

#define SSIMADD do {                                                \
        float p12 = S1 * S2;                                        \
        float q1  = S1 * S1, q2 = S2 * S2;                          \
        float A1  = fmaf(2.f, p12, C1s);                            \
        float B1  = q1 + q2 + C1s;                                  \
        float mtp = fmaf(49.f, S5, -p12);                           \
        float A2  = fmaf(2.f, mtp, C2s);                            \
        float mtt = fmaf(49.f, S3, -q1);                            \
        float mpp = fmaf(49.f, S4, -q2);                            \
        float B2  = mtt + mpp + C2s;                                \
        acc += __fdividef(A1 * A2, B1 * B2);                        \
    } while (0)

#define STEP(K, GLOAD, GWRITE) do {                                 \
        int sl = se + 3; if (sl >= NSLOT) sl -= NSLOT;              \
        int s1 = se + 1; if (s1 >= NSLOT) s1 -= NSLOT;              \
        int sw = se + 2; if (sw >= NSLOT) sw -= NSLOT;              \
        /* 1) leave-reads issued first (hidden under enter-apply) */ \
        float2 la0, la1, la2, la3, lc0, lc1, lc2, lc3;              \
        if ((K) >= 7) {                                             \
            la0 = *(const float2*)&ring[sl][0][rc + 0];             \
            la1 = *(const float2*)&ring[sl][0][rc + 2];             \
            la2 = *(const float2*)&ring[sl][0][rc + 4];             \
            la3 = *(const float2*)&ring[sl][0][rc + 6];             \
            lc0 = *(const float2*)&ring[sl][1][rc + 0];             \
            lc1 = *(const float2*)&ring[sl][1][rc + 2];             \
            lc2 = *(const float2*)&ring[sl][1][rc + 4];             \
            lc3 = *(const float2*)&ring[sl][1][rc + 6];             \
        }                                                           \
        /* 2) global load row K+3 (consumed next iter) */           \
        if ((K) + 3 <= lastr) GLOAD = *(const float4*)(gsrc + ((K) + 3) * NW); \
        /* 3) apply enter row K from prefetched regs (0-stall) */   \
        APPLY2(0, ea0, ec0, +); APPLY2(2, ea1, ec1, +);             \
        APPLY2(4, ea2, ec2, +); APPLY2(6, ea3, ec3, +);             \
        /* 4) prefetch enter row K+1 (slot valid since last barrier) */ \
        if ((K) + 1 < kend) {                                       \
            ea0 = *(const float2*)&ring[s1][0][rc + 0];             \
            ea1 = *(const float2*)&ring[s1][0][rc + 2];             \
            ea2 = *(const float2*)&ring[s1][0][rc + 4];             \
            ea3 = *(const float2*)&ring[s1][0][rc + 6];             \
            ec0 = *(const float2*)&ring[s1][1][rc + 0];             \
            ec1 = *(const float2*)&ring[s1][1][rc + 2];             \
            ec2 = *(const float2*)&ring[s1][1][rc + 4];             \
            ec3 = *(const float2*)&ring[s1][1][rc + 6];             \
        }                                                           \
        /* 5) apply leave row K-7 */                                \
        if ((K) >= 7) {                                             \
            APPLY2(0, la0, lc0, -); APPLY2(2, la1, lc1, -);         \
            APPLY2(4, la2, lc2, -); APPLY2(6, la3, lc3, -);         \
        }                                                           \
        /* 6) emit output row K-6 (cols 2li, 2li+1) */              \
        if ((K) >= 6 && valid) {                                    \
            float S1 = st[0]+st[1]+st[2]+st[3]+st[4]+st[5]+st[6];   \
            float S2 = sp[0]+sp[1]+sp[2]+sp[3]+sp[4]+sp[5]+sp[6];   \
            float S3 = stt[0]+stt[1]+stt[2]+stt[3]+stt[4]+stt[5]+stt[6]; \
            float S4 = spp[0]+spp[1]+spp[2]+spp[3]+spp[4]+spp[5]+spp[6]; \
            float S5 = stp[0]+stp[1]+stp[2]+stp[3]+stp[4]+stp[5]+stp[6]; \
            SSIMADD;                                                \
            S1 += st[7]  - st[0];                                   \
            S2 += sp[7]  - sp[0];                                   \
            S3 += stt[7] - stt[0];                                  \
            S4 += spp[7] - spp[0];                                  \
            S5 += stp[7] - stp[0];                                  \
            SSIMADD;                                                \
        }                                                           \
        /* 7) write row K+2 (loaded at iter K-1) */                 \
        if ((K) + 2 <= lastr) *(float4*)&ring[sw][sarr][scol] = GWRITE; \
        /* 8) one barrier per iter */                               \
        __syncthreads();                                            \
        if (++se == NSLOT) se = 0;                                  \
    } while (0)

    int k = 0;
    while (true) {
        STEP(k, gE, gO); if (++k >= kend) break;   // even k: load gE, write gO
        STEP(k, gO, gE); if (++k >= kend) break;   // odd  k: load gO, write gE
    }

#undef STEP
#undef SSIMADD
#undef APPLY2

    // final reduction (ring is dead; last STEP ended with a barrier)
    #pragma unroll
    for (int off = 32; off; off >>= 1) acc += __shfl_down(acc, off, 64);
    if ((li & 63) == 0) ((float*)ring)[li >> 6] = acc;
    __syncthreads();
    if (li == 0) {
        float* r = (float*)ring;
        atomicAdd(&sum[b], r[0] + r[1] + r[2] + r[3]);
    }
}

// -------- kernel 3: finalize mean
__global__ void ssim_finalize(const float* __restrict__ sum, float* __restrict__ out) {
    int i = threadIdx.x;
    if (i < NB) out[i] = sum[i] / (float)(NC * OUTH * OUTW);
}

extern "C" void kernel_launch(void* const* d_in, const int* in_sizes, int n_in,
                              void* d_out, int out_size, void* d_ws, size_t ws_size,
                              hipStream_t stream) {
    const float* t = (const float*)d_in[0];   // true
    const float* p = (const float*)d_in[1];   // pred
    float* out = (float*)d_out;

    unsigned int* mn  = (unsigned int*)d_ws;
    unsigned int* mx  = mn + NB;
    float*        sum = (float*)(mx + NB);

    ssim_init_ws<<<1, 64, 0, stream>>>(mn, mx, sum);
    ssim_minmax<<<dim3(64, NB), 256, 0, stream>>>(p, mn, mx);

    // 1008 blocks (16 img x 3 ch x 21 row-chunks), 4 waves/block, 40 KB LDS
    ssim_main<<<dim3(NBLK), 256, 0, stream>>>(t, p, mn, mx, sum);

    ssim_finalize<<<1, 64, 0, stream>>>(sum, out);
}

// Round 10
// 66.917 us; speedup vs baseline: 1.0030x; 1.0030x over previous
//
#include <hip/hip_runtime.h>

#define NB   16
#define NC   3
#define NH   512
#define NW   512
#define OUTH 506
#define OUTW 506
#define NCHK 21          // 19 chunks x 24 rows + 2 chunks x 25 rows = 506
#define NSLOT 10         // ring slots; 2-rows-ahead staging (see race analysis)
#define NBLK (NB * NC * NCHK)   // 1008 blocks

// LDS-visibility barrier WITHOUT the vmcnt(0) drain of __syncthreads():
// ds ops are drained (lgkmcnt), in-flight global loads stay in flight.
#define LDS_BARRIER() do {                                   \
        asm volatile("s_waitcnt lgkmcnt(0)" ::: "memory");   \
        __builtin_amdgcn_s_barrier();                        \
    } while (0)

// -------- kernel 0: init workspace (runs every call; harness doesn't re-poison)
__global__ void ssim_init_ws(unsigned int* mn, unsigned int* mx, float* sum) {
    int i = threadIdx.x;
    if (i < NB) { mn[i] = 0x7f7fffffu; mx[i] = 0u; sum[i] = 0.0f; }
}

// -------- kernel 1: per-image min/max of pred (values >= 0 -> uint-bit order == float order)
__global__ __launch_bounds__(256) void ssim_minmax(const float* __restrict__ pred,
                                                   unsigned int* __restrict__ mn,
                                                   unsigned int* __restrict__ mx) {
    int b = blockIdx.y;
    const float4* p4 = (const float4*)(pred + (size_t)b * (NC * NH * NW));
    const int n4 = (NC * NH * NW) / 4;
    float lmin = 3.4e38f, lmax = -3.4e38f;
    for (int i = blockIdx.x * blockDim.x + threadIdx.x; i < n4; i += gridDim.x * blockDim.x) {
        float4 v = p4[i];
        lmin = fminf(lmin, fminf(fminf(v.x, v.y), fminf(v.z, v.w)));
        lmax = fmaxf(lmax, fmaxf(fmaxf(v.x, v.y), fmaxf(v.z, v.w)));
    }
    #pragma unroll
    for (int off = 32; off; off >>= 1) {
        lmin = fminf(lmin, __shfl_down(lmin, off, 64));
        lmax = fmaxf(lmax, __shfl_down(lmax, off, 64));
    }
    __shared__ float smin[4], smax[4];
    int wid = threadIdx.x >> 6, lane = threadIdx.x & 63;
    if (lane == 0) { smin[wid] = lmin; smax[wid] = lmax; }
    __syncthreads();
    if (threadIdx.x == 0) {
        float m = fminf(fminf(smin[0], smin[1]), fminf(smin[2], smin[3]));
        float M = fmaxf(fmaxf(smax[0], smax[1]), fmaxf(smax[2], smax[3]));
        atomicMin(&mn[b], __float_as_uint(m));
        atomicMax(&mx[b], __float_as_uint(M));
    }
}

// -------- kernel 2: LDS-ring SSIM, software-pipelined
// Ring race analysis (N=10, 2-ahead staging, 1 barrier/iter):
//   iter k: leave-reads slot (k+3)%10 (row k-7), enter-prefetch slot (k+1)%10
//           (row k+1, written at iter k-1, valid since barrier k-1),
//           writes slot (k+2)%10 (row k+2, loaded at iter k-1) -> disjoint.
//   slot (k+2)%10 last held row k-8, last read (leave) at iter k-1,
//   separated from the write by the end-of-iter-(k-1) barrier.
// NOTE: no min-waves launch_bounds (R4/R9: it makes hipcc cap VGPR at 64 and
// spill); occupancy is LDS-limited to 4 blocks/CU anyway (4 x 40KB = 160KB).
__global__ __launch_bounds__(256) void ssim_main(const float* __restrict__ tin,
                                                 const float* __restrict__ pin,
                                                 const unsigned int* __restrict__ mn,
                                                 const unsigned int* __restrict__ mx,
                                                 float* __restrict__ sum) {
    __shared__ float ring[NSLOT][2][NW];   // 40,960 B exactly -> 4 blocks/CU

    const int li    = threadIdx.x;
    const int imgch = blockIdx.x / NCHK;
    const int chunk = blockIdx.x - imgch * NCHK;
    const int b     = imgch / NC;
    const int r0    = chunk * 24 + max(0, chunk - 19);  // chunks 19,20 have 25 rows
    const int rpc   = (chunk >= 19) ? 25 : 24;
    const int kend  = rpc + 6;
    const int lastr = rpc + 5;

    const float* tbase = tin + (size_t)imgch * (NH * NW) + (size_t)r0 * NW;
    const float* pbase = pin + (size_t)imgch * (NH * NW) + (size_t)r0 * NW;

    const float dr  = __uint_as_float(mx[b]) - __uint_as_float(mn[b]);
    const float c1  = (0.01f * dr) * (0.01f * dr);
    const float c2  = (0.03f * dr) * (0.03f * dr);
    const float C1s = 2401.0f * c1;   // 49^2 * c1
    const float C2s = 2352.0f * c2;   // 48*49 * c2

    // staging role: waves 0-1 stage t rows, waves 2-3 stage p rows (float4)
    const int  sarr = (li < 128) ? 0 : 1;
    const int  scol = (li & 127) * 4;
    const float* gsrc = ((sarr == 0) ? tbase : pbase) + scol;

    // read-column base; threads 253-255 clamp (outputs masked)
    const int rc = 2 * min(li, 252);
    const bool valid = (li < 253);

    float st[8], sp[8], stt[8], spp[8], stp[8];
    #pragma unroll
    for (int i = 0; i < 8; ++i) { st[i]=0.f; sp[i]=0.f; stt[i]=0.f; spp[i]=0.f; stp[i]=0.f; }

    float acc = 0.f;

    // prologue: stage rows 0,1 into slots 0,1; row 2 -> gO (as if loaded iter -1)
    {
        float4 r0v = *(const float4*)(gsrc);
        float4 r1v = *(const float4*)(gsrc + NW);
        *(float4*)&ring[0][sarr][scol] = r0v;
        *(float4*)&ring[1][sarr][scol] = r1v;
    }
    float4 gO = *(const float4*)(gsrc + 2 * NW);
    float4 gE;
    __syncthreads();

    // prefetched enter registers (row k at iter k), filled for row 0 now
    float2 ea0, ea1, ea2, ea3, ec0, ec1, ec2, ec3;
    ea0 = *(const float2*)&ring[0][0][rc + 0];
    ea1 = *(const float2*)&ring[0][0][rc + 2];
    ea2 = *(const float2*)&ring[0][0][rc + 4];
    ea3 = *(const float2*)&ring[0][0][rc + 6];
    ec0 = *(const float2*)&ring[0][1][rc + 0];
    ec1 = *(const float2*)&ring[0][1][rc + 2];
    ec2 = *(const float2*)&ring[0][1][rc + 4];
    ec3 = *(const float2*)&ring[0][1][rc + 6];

    int se = 0;   // k % NSLOT

#define APPLY2(I0, A_, C_, SGN) do {                                \
        st[I0]     += SGN A_.x;  sp[I0]     += SGN C_.x;            \
        stt[I0]     = fmaf(SGN A_.x, A_.x, stt[I0]);                \
        spp[I0]     = fmaf(SGN C_.x, C_.x, spp[I0]);                \
        stp[I0]     = fmaf(SGN A_.x, C_.x, stp[I0]);                \
        st[I0 + 1] += SGN A_.y;  sp[I0 + 1] += SGN C_.y;            \
        stt[I0 + 1] = fmaf(SGN A_.y, A_.y, stt[I0 + 1]);            \
        spp[I0 + 1] = fmaf(SGN C_.y, C_.y, spp[I0 + 1]);            \
        stp[I0 + 1] = fmaf(SGN A_.y, C_.y, stp[I0 + 1]);            \
    } while (0)

#define SSIMADD do {                                                \
        float p12 = S1 * S2;                                        \
        float q1  = S1 * S1, q2 = S2 * S2;                          \
        float A1  = fmaf(2.f, p12, C1s);                            \
        float B1  = q1 + q2 + C1s;                                  \
        float mtp = fmaf(49.f, S5, -p12);                           \
        float A2  = fmaf(2.f, mtp, C2s);                            \
        float mtt = fmaf(49.f, S3, -q1);                            \
        float mpp = fmaf(49.f, S4, -q2);                            \
        float B2  = mtt + mpp + C2s;                                \
        acc += __fdividef(A1 * A2, B1 * B2);                        \
    } while (0)

#define STEP(K, GLOAD, GWRITE) do {                                 \
        int sl = se + 3; if (sl >= NSLOT) sl -= NSLOT;              \
        int s1 = se + 1; if (s1 >= NSLOT) s1 -= NSLOT;              \
        int sw = se + 2; if (sw >= NSLOT) sw -= NSLOT;              \
        /* 1) leave-reads issued first (hidden under enter-apply) */ \
        float2 la0, la1, la2, la3, lc0, lc1, lc2, lc3;              \
        if ((K) >= 7) {                                             \
            la0 = *(const float2*)&ring[sl][0][rc + 0];             \
            la1 = *(const float2*)&ring[sl][0][rc + 2];             \
            la2 = *(const float2*)&ring[sl][0][rc + 4];             \
            la3 = *(const float2*)&ring[sl][0][rc + 6];             \
            lc0 = *(const float2*)&ring[sl][1][rc + 0];             \
            lc1 = *(const float2*)&ring[sl][1][rc + 2];             \
            lc2 = *(const float2*)&ring[sl][1][rc + 4];             \
            lc3 = *(const float2*)&ring[sl][1][rc + 6];             \
        }                                                           \
        /* 2) global load row K+3 (consumed next iter; stays in    */ \
        /*    flight across the lgkm-only barrier)                 */ \
        if ((K) + 3 <= lastr) GLOAD = *(const float4*)(gsrc + ((K) + 3) * NW); \
        /* 3) apply enter row K from prefetched regs (0-stall) */   \
        APPLY2(0, ea0, ec0, +); APPLY2(2, ea1, ec1, +);             \
        APPLY2(4, ea2, ec2, +); APPLY2(6, ea3, ec3, +);             \
        /* 4) prefetch enter row K+1 (slot valid since last barrier) */ \
        if ((K) + 1 < kend) {                                       \
            ea0 = *(const float2*)&ring[s1][0][rc + 0];             \
            ea1 = *(const float2*)&ring[s1][0][rc + 2];             \
            ea2 = *(const float2*)&ring[s1][0][rc + 4];             \
            ea3 = *(const float2*)&ring[s1][0][rc + 6];             \
            ec0 = *(const float2*)&ring[s1][1][rc + 0];             \
            ec1 = *(const float2*)&ring[s1][1][rc + 2];             \
            ec2 = *(const float2*)&ring[s1][1][rc + 4];             \
            ec3 = *(const float2*)&ring[s1][1][rc + 6];             \
        }                                                           \
        /* 5) apply leave row K-7 */                                \
        if ((K) >= 7) {                                             \
            APPLY2(0, la0, lc0, -); APPLY2(2, la1, lc1, -);         \
            APPLY2(4, la2, lc2, -); APPLY2(6, la3, lc3, -);         \
        }                                                           \
        /* 6) emit output row K-6 (cols 2li, 2li+1) */              \
        if ((K) >= 6 && valid) {                                    \
            float S1 = st[0]+st[1]+st[2]+st[3]+st[4]+st[5]+st[6];   \
            float S2 = sp[0]+sp[1]+sp[2]+sp[3]+sp[4]+sp[5]+sp[6];   \
            float S3 = stt[0]+stt[1]+stt[2]+stt[3]+stt[4]+stt[5]+stt[6]; \
            float S4 = spp[0]+spp[1]+spp[2]+spp[3]+spp[4]+spp[5]+spp[6]; \
            float S5 = stp[0]+stp[1]+stp[2]+stp[3]+stp[4]+stp[5]+stp[6]; \
            SSIMADD;                                                \
            S1 += st[7]  - st[0];                                   \
            S2 += sp[7]  - sp[0];                                   \
            S3 += stt[7] - stt[0];                                  \
            S4 += spp[7] - spp[0];                                  \
            S5 += stp[7] - stp[0];                                  \
            SSIMADD;                                                \
        }                                                           \
        /* 7) write row K+2 (loaded at iter K-1; vmcnt dep only here) */ \
        if ((K) + 2 <= lastr) *(float4*)&ring[sw][sarr][scol] = GWRITE; \
        /* 8) lgkm-only barrier: LDS ordered, global loads NOT drained */ \
        LDS_BARRIER();                                              \
        if (++se == NSLOT) se = 0;                                  \
    } while (0)

    int k = 0;
    while (true) {
        STEP(k, gE, gO); if (++k >= kend) break;   // even k: load gE, write gO
        STEP(k, gO, gE); if (++k >= kend) break;   // odd  k: load gO, write gE
    }

#undef STEP
#undef SSIMADD
#undef APPLY2

    // final reduction (ring is dead; last STEP ended with a barrier)
    #pragma unroll
    for (int off = 32; off; off >>= 1) acc += __shfl_down(acc, off, 64);
    if ((li & 63) == 0) ((float*)ring)[li >> 6] = acc;
    __syncthreads();
    if (li == 0) {
        float* r = (float*)ring;
        atomicAdd(&sum[b], r[0] + r[1] + r[2] + r[3]);
    }
}

// -------- kernel 3: finalize mean
__global__ void ssim_finalize(const float* __restrict__ sum, float* __restrict__ out) {
    int i = threadIdx.x;
    if (i < NB) out[i] = sum[i] / (float)(NC * OUTH * OUTW);
}

extern "C" void kernel_launch(void* const* d_in, const int* in_sizes, int n_in,
                              void* d_out, int out_size, void* d_ws, size_t ws_size,
                              hipStream_t stream) {
    const float* t = (const float*)d_in[0];   // true
    const float* p = (const float*)d_in[1];   // pred
    float* out = (float*)d_out;

    unsigned int* mn  = (unsigned int*)d_ws;
    unsigned int* mx  = mn + NB;
    float*        sum = (float*)(mx + NB);

    ssim_init_ws<<<1, 64, 0, stream>>>(mn, mx, sum);
    ssim_minmax<<<dim3(64, NB), 256, 0, stream>>>(p, mn, mx);

    // 1008 blocks (16 img x 3 ch x 21 row-chunks), 4 waves/block, 40 KB LDS
    ssim_main<<<dim3(NBLK), 256, 0, stream>>>(t, p, mn, mx, sum);

    ssim_finalize<<<1, 64, 0, stream>>>(sum, out);
}

// Round 11
// 50.636 us; speedup vs baseline: 1.3255x; 1.3215x over previous
//
#include <hip/hip_runtime.h>

#define NB   16
#define NC   3
#define NH   512
#define NW   512
#define OUTH 506
#define OUTW 506
#define NCHK 21          // 19 chunks x 24 rows + 2 chunks x 25 rows = 506
#define NSLOT 10         // ring slots; 2-ahead staging (race algebra as R9/R10)
#define NBLK (NB * NC * NCHK)   // 1008 blocks
#define BPI  (NC * NCHK)        // 63 blocks per image
#define MMB  64                 // minmax partial blocks per image

// LDS-visibility barrier WITHOUT the vmcnt(0) drain of __syncthreads()
#define LDS_BARRIER() do {                                   \
        asm volatile("s_waitcnt lgkmcnt(0)" ::: "memory");   \
        __builtin_amdgcn_s_barrier();                        \
    } while (0)

// -------- kernel 1: per-image min/max partials (no atomics -> no init kernel)
__global__ __launch_bounds__(256) void ssim_minmax(const float* __restrict__ pred,
                                                   float* __restrict__ mnp,
                                                   float* __restrict__ mxp) {
    int b = blockIdx.y;
    const float4* p4 = (const float4*)(pred + (size_t)b * (NC * NH * NW));
    const int n4 = (NC * NH * NW) / 4;
    float lmin = 3.4e38f, lmax = -3.4e38f;
    for (int i = blockIdx.x * blockDim.x + threadIdx.x; i < n4; i += gridDim.x * blockDim.x) {
        float4 v = p4[i];
        lmin = fminf(lmin, fminf(fminf(v.x, v.y), fminf(v.z, v.w)));
        lmax = fmaxf(lmax, fmaxf(fmaxf(v.x, v.y), fmaxf(v.z, v.w)));
    }
    #pragma unroll
    for (int off = 32; off; off >>= 1) {
        lmin = fminf(lmin, __shfl_down(lmin, off, 64));
        lmax = fmaxf(lmax, __shfl_down(lmax, off, 64));
    }
    __shared__ float smin[4], smax[4];
    int wid = threadIdx.x >> 6, lane = threadIdx.x & 63;
    if (lane == 0) { smin[wid] = lmin; smax[wid] = lmax; }
    __syncthreads();
    if (threadIdx.x == 0) {
        mnp[b * MMB + blockIdx.x] = fminf(fminf(smin[0], smin[1]), fminf(smin[2], smin[3]));
        mxp[b * MMB + blockIdx.x] = fmaxf(fmaxf(smax[0], smax[1]), fmaxf(smax[2], smax[3]));
    }
}

// -------- kernel 2: LDS-ring SSIM, 4 cols/thread, all-b128 LDS traffic
// Block = 128 threads (2 waves) = one (imgch, 24/25-row chunk), 512 cols.
// Thread li owns output cols 4li..4li+3, tracks 12 cols via 3 aligned b128
// reads per array. Wave 0 stages t rows, wave 1 stages p rows (8 floats/thr).
// Ring race algebra (N=10, 1 lgkm-barrier/iter) identical to R9/R10:
//   iter k: leave-reads slot (k+3)%10 (row k-7), enter-prefetch slot (k+1)%10,
//   writes slot (k+2)%10 (row k+2, loaded at iter k-1) — all disjoint; the
//   written slot's last reader was iter k-1 (barrier-separated).
__global__ __launch_bounds__(128, 2) void ssim_main(const float* __restrict__ tin,
                                                    const float* __restrict__ pin,
                                                    const float* __restrict__ mnp,
                                                    const float* __restrict__ mxp,
                                                    float* __restrict__ bsum) {
    __shared__ float ring[NSLOT][2][NW];   // 40,960 B exactly -> 4 blocks/CU

    const int li    = threadIdx.x;         // 0..127
    const int lane  = li & 63;
    const int imgch = blockIdx.x / NCHK;
    const int chunk = blockIdx.x - imgch * NCHK;
    const int b     = imgch / NC;
    const int r0    = chunk * 24 + max(0, chunk - 19);  // chunks 19,20: 25 rows
    const int rpc   = (chunk >= 19) ? 25 : 24;
    const int kend  = rpc + 6;
    const int lastr = rpc + 5;

    // per-image range from 64 partials: 6-level butterfly, every lane gets it
    float mnv = mnp[b * MMB + lane], mxv = mxp[b * MMB + lane];
    #pragma unroll
    for (int m = 1; m < 64; m <<= 1) {
        mnv = fminf(mnv, __shfl_xor(mnv, m, 64));
        mxv = fmaxf(mxv, __shfl_xor(mxv, m, 64));
    }
    const float dr  = mxv - mnv;
    const float c1  = (0.01f * dr) * (0.01f * dr);
    const float c2  = (0.03f * dr) * (0.03f * dr);
    const float C1s = 2401.0f * c1;   // 49^2 * c1
    const float C2s = 2352.0f * c2;   // 48*49 * c2

    const float* tbase = tin + (size_t)imgch * (NH * NW) + (size_t)r0 * NW;
    const float* pbase = pin + (size_t)imgch * (NH * NW) + (size_t)r0 * NW;

    // staging: wave 0 -> t array, wave 1 -> p array; 8 consecutive floats each
    const int  sarr = (li < 64) ? 0 : 1;
    const int  scol = lane * 8;
    const float* gsrc = ((sarr == 0) ? tbase : pbase) + scol;

    // compute ownership: 4 cols, 12 tracked, aligned b128 bases (clamps only
    // affect tracked slots that feed masked >=OUTW outputs)
    const int rc  = 4 * li;                 // 0..508
    const int cb1 = min(rc + 4, NW - 4);
    const int cb2 = min(rc + 8, NW - 4);

    float s1[10], s2[10], s3[10], s4[10], s5[10];
    #pragma unroll
    for (int i = 0; i < 10; ++i) { s1[i]=0.f; s2[i]=0.f; s3[i]=0.f; s4[i]=0.f; s5[i]=0.f; }

    float acc = 0.f;

    // prologue: stage rows 0,1; row 2 -> gB (as if loaded at iter -1)
    {
        float4 a0 = *(const float4*)(gsrc);
        float4 a1 = *(const float4*)(gsrc + 4);
        float4 b0 = *(const float4*)(gsrc + NW);
        float4 b1 = *(const float4*)(gsrc + NW + 4);
        *(float4*)&ring[0][sarr][scol]     = a0;
        *(float4*)&ring[0][sarr][scol + 4] = a1;
        *(float4*)&ring[1][sarr][scol]     = b0;
        *(float4*)&ring[1][sarr][scol + 4] = b1;
    }
    float4 gB0 = *(const float4*)(gsrc + 2 * NW);
    float4 gB1 = *(const float4*)(gsrc + 2 * NW + 4);
    float4 gA0, gA1;
    __syncthreads();

#define LOADT(TE, PE, S) do {                                       \
        *(float4*)&TE[0] = *(const float4*)&ring[S][0][rc];         \
        *(float4*)&TE[4] = *(const float4*)&ring[S][0][cb1];        \
        *(float4*)&TE[8] = *(const float4*)&ring[S][0][cb2];        \
        *(float4*)&PE[0] = *(const float4*)&ring[S][1][rc];         \
        *(float4*)&PE[4] = *(const float4*)&ring[S][1][cb1];        \
        *(float4*)&PE[8] = *(const float4*)&ring[S][1][cb2];        \
    } while (0)

#define APPLY(TE, PE, SGN) do {                                     \
        _Pragma("unroll")                                           \
        for (int i = 0; i < 10; ++i) {                              \
            float t_ = TE[i], p_ = PE[i];                           \
            s1[i] += SGN t_;  s2[i] += SGN p_;                      \
            s3[i] = fmaf(SGN t_, t_, s3[i]);                        \
            s4[i] = fmaf(SGN p_, p_, s4[i]);                        \
            s5[i] = fmaf(SGN t_, p_, s5[i]);                        \
        }                                                           \
    } while (0)

#define SSIMADD(C) do {                                             \
        if (rc + (C) < OUTW) {                                      \
            float p12 = S1 * S2;                                    \
            float q1  = S1 * S1, q2 = S2 * S2;                      \
            float A1  = fmaf(2.f, p12, C1s);                        \
            float B1  = q1 + q2 + C1s;                              \
            float mtp = fmaf(49.f, S5, -p12);                       \
            float A2  = fmaf(2.f, mtp, C2s);                        \
            float mtt = fmaf(49.f, S3, -q1);                        \
            float mpp = fmaf(49.f, S4, -q2);                        \
            float B2  = mtt + mpp + C2s;                            \
            acc += __fdividef(A1 * A2, B1 * B2);                    \
        }                                                           \
    } while (0)

#define EMIT do {                                                   \
        float S1 = s1[0]+s1[1]+s1[2]+s1[3]+s1[4]+s1[5]+s1[6];       \
        float S2 = s2[0]+s2[1]+s2[2]+s2[3]+s2[4]+s2[5]+s2[6];       \
        float S3 = s3[0]+s3[1]+s3[2]+s3[3]+s3[4]+s3[5]+s3[6];       \
        float S4 = s4[0]+s4[1]+s4[2]+s4[3]+s4[4]+s4[5]+s4[6];       \
        float S5 = s5[0]+s5[1]+s5[2]+s5[3]+s5[4]+s5[5]+s5[6];       \
        SSIMADD(0);                                                 \
        _Pragma("unroll")                                           \
        for (int c = 1; c < 4; ++c) {                               \
            S1 += s1[c+6] - s1[c-1];                                \
            S2 += s2[c+6] - s2[c-1];                                \
            S3 += s3[c+6] - s3[c-1];                                \
            S4 += s4[c+6] - s4[c-1];                                \
            S5 += s5[c+6] - s5[c-1];                                \
            SSIMADD(c);                                             \
        }                                                           \
    } while (0)

    // persistent enter-prefetch registers; fill for row 0
    float et[12], ep[12];
    LOADT(et, ep, 0);

    int se = 0;   // k % NSLOT

#define STEP(K, GL0, GL1, GW0, GW1) do {                            \
        int sl  = se + 3; if (sl  >= NSLOT) sl  -= NSLOT;           \
        int sn  = se + 1; if (sn  >= NSLOT) sn  -= NSLOT;           \
        int sw  = se + 2; if (sw  >= NSLOT) sw  -= NSLOT;           \
        /* global load row K+3 (stays in flight across barriers) */ \
        if ((K) + 3 <= lastr) {                                     \
            GL0 = *(const float4*)(gsrc + ((K) + 3) * NW);          \
            GL1 = *(const float4*)(gsrc + ((K) + 3) * NW + 4);      \
        }                                                           \
        /* leave-reads issued early, consumed after enter-apply */  \
        float lt[12], lp[12];                                       \
        if ((K) >= 7) LOADT(lt, lp, sl);                            \
        /* enter row K from prefetched regs (0-stall) */            \
        APPLY(et, ep, +);                                           \
        /* prefetch enter row K+1 (slot valid since last barrier) */ \
        if ((K) + 1 < kend) LOADT(et, ep, sn);                      \
        if ((K) >= 7) APPLY(lt, lp, -);                             \
        if ((K) >= 6) { EMIT; }                                     \
        /* write row K+2 (loaded at iter K-1; reg-dep vmcnt only) */ \
        if ((K) + 2 <= lastr) {                                     \
            *(float4*)&ring[sw][sarr][scol]     = GW0;              \
            *(float4*)&ring[sw][sarr][scol + 4] = GW1;              \
        }                                                           \
        LDS_BARRIER();                                              \
        if (++se == NSLOT) se = 0;                                  \
    } while (0)

    int k = 0;
    while (true) {
        STEP(k, gA0, gA1, gB0, gB1); if (++k >= kend) break;
        STEP(k, gB0, gB1, gA0, gA1); if (++k >= kend) break;
    }

#undef STEP
#undef EMIT
#undef SSIMADD
#undef APPLY
#undef LOADT

    // per-block partial (deterministic, no atomics); ring is dead after loop
    #pragma unroll
    for (int off = 32; off; off >>= 1) acc += __shfl_down(acc, off, 64);
    if (lane == 0) ((float*)ring)[li >> 6] = acc;
    __syncthreads();
    if (li == 0) {
        float* r = (float*)ring;
        bsum[blockIdx.x] = r[0] + r[1];
    }
}

// -------- kernel 3: finalize per-image mean from 63 block partials
__global__ void ssim_finalize(const float* __restrict__ bsum, float* __restrict__ out) {
    int b = blockIdx.x, lane = threadIdx.x;
    float v = (lane < BPI) ? bsum[b * BPI + lane] : 0.0f;
    #pragma unroll
    for (int off = 32; off; off >>= 1) v += __shfl_down(v, off, 64);
    if (lane == 0) out[b] = v / (float)(NC * OUTH * OUTW);
}

extern "C" void kernel_launch(void* const* d_in, const int* in_sizes, int n_in,
                              void* d_out, int out_size, void* d_ws, size_t ws_size,
                              hipStream_t stream) {
    const float* t = (const float*)d_in[0];   // true
    const float* p = (const float*)d_in[1];   // pred
    float* out = (float*)d_out;

    float* mnp  = (float*)d_ws;               // 1024 floats
    float* mxp  = mnp + NB * MMB;             // 1024 floats
    float* bsum = mxp + NB * MMB;             // 1008 floats

    ssim_minmax<<<dim3(MMB, NB), 256, 0, stream>>>(p, mnp, mxp);
    ssim_main<<<dim3(NBLK), 128, 0, stream>>>(t, p, mnp, mxp, bsum);
    ssim_finalize<<<dim3(NB), 64, 0, stream>>>(bsum, out);
}